// Round 1
// 1222.984 us; speedup vs baseline: 1.3813x; 1.3813x over previous
//
#include <hip/hip_runtime.h>
#include <hip/hip_bf16.h>
#include <stdint.h>

#define M_DIM 8192
#define N_DIM 11008
#define K_DIM 4096
#define KBYTES (K_DIM * 2)   // bf16 row bytes

typedef __bf16 bf16x8 __attribute__((ext_vector_type(8)));
typedef float floatx4 __attribute__((ext_vector_type(4)));

__device__ __forceinline__ void async_copy16(const void* g, void* l) {
    __builtin_amdgcn_global_load_lds(
        (const __attribute__((address_space(1))) unsigned int*)g,
        (__attribute__((address_space(3))) unsigned int*)l,
        16, 0, 0);
}

// ---- prepass: x fp32 -> bf16 (8 elems/thread) ----
__global__ void cvt_x_kernel(const float* __restrict__ x, bf16x8* __restrict__ o) {
    int i = blockIdx.x * 256 + threadIdx.x;
    const float4* xv = (const float4*)x;
    float4 a = xv[2 * (size_t)i];
    float4 b = xv[2 * (size_t)i + 1];
    bf16x8 v;
    v[0] = (__bf16)a.x; v[1] = (__bf16)a.y; v[2] = (__bf16)a.z; v[3] = (__bf16)a.w;
    v[4] = (__bf16)b.x; v[5] = (__bf16)b.y; v[6] = (__bf16)b.z; v[7] = (__bf16)b.w;
    o[i] = v;
}

// ---- prepass: W fp32 -> bf16 with fused block-dequant scale ----
__global__ void cvt_w_kernel(const float* __restrict__ w, const float* __restrict__ s,
                             bf16x8* __restrict__ o) {
    int i = blockIdx.x * 256 + threadIdx.x;   // one thread = 8 consecutive k
    int n  = i >> 9;          // K_DIM/8 = 512 threads per row
    int k8 = i & 511;
    float sc = s[(n >> 7) * 32 + (k8 >> 4)];
    const float4* wv = (const float4*)w;
    float4 a = wv[2 * (size_t)i];
    float4 b = wv[2 * (size_t)i + 1];
    bf16x8 v;
    v[0] = (__bf16)(a.x * sc); v[1] = (__bf16)(a.y * sc);
    v[2] = (__bf16)(a.z * sc); v[3] = (__bf16)(a.w * sc);
    v[4] = (__bf16)(b.x * sc); v[5] = (__bf16)(b.y * sc);
    v[6] = (__bf16)(b.z * sc); v[7] = (__bf16)(b.w * sc);
    o[i] = v;
}

// ---- GEMM: C[m][n] = sum_k A[m][k]*B[n][k]; A MxK bf16, B NxK bf16, C MxN fp32.
// 256x256 tile, BK=32, 8 waves (2M x 4N), wave = 128x64 out (8x4 frags of 16x16x32).
// LDS: 4-slot K-tile ring (A 4x16KB @0, B 4x16KB @64KB) = 128 KB.
// Pipeline: stage tile t+3 while computing tile t; s_waitcnt vmcnt(8) + raw s_barrier
// per tile (loads stay in flight across barriers — no vmcnt(0) drain in main loop).
// LDS permutation (involution on 16B chunks, applied to BOTH stage-source and read):
//   phys(m,k8) = (m>>1)*128 + ((2*k8 + (m&1)) ^ ((m>>1)&7))*16
// -> ds_read_b128 of 16 consecutive rows covers all 8 slots 2x (2-way = free).
__global__ __launch_bounds__(512, 2) void gemm_bt_kernel(const __bf16* __restrict__ A,
                                                         const __bf16* __restrict__ B,
                                                         float* __restrict__ C) {
    __shared__ char lds[131072];   // 128 KB: A ring @0, B ring @65536

    const int t    = threadIdx.x;
    const int lane = t & 63;
    const int wave = t >> 6;
    const int r    = lane & 15;
    const int quad = lane >> 4;
    const int wm   = (wave >> 2) * 128;   // 2 M-waves
    const int wn   = (wave & 3) * 64;     // 4 N-waves

    // XCD-aware bijective swizzle: 1376 blocks = 8 XCDs x 172
    const int nper = gridDim.x >> 3;                 // 172
    const int bid  = blockIdx.x;
    const int swz  = (bid & 7) * nper + (bid >> 3);
    const int tm   = (swz / (N_DIM / 256)) * 256;
    const int tn   = (swz % (N_DIM / 256)) * 256;

    // ---- per-thread staging descriptors (constant across K-tiles) ----
    // chunk cp = (wave*2+j)*64 + lane holds logical (m,k8) = inverse of phys():
    //   p = cp>>3; y = (cp&7)^(p&7); m = 2p + (y&1); k8 = y>>1
    const char* gsrc[4];
    char*       ldst[4];
    {
        const char* gA = (const char*)(A + (size_t)tm * K_DIM);
        const char* gB = (const char*)(B + (size_t)tn * K_DIM);
#pragma unroll
        for (int j = 0; j < 2; ++j) {
            int cp = (wave * 2 + j) * 64 + lane;
            int p  = cp >> 3;
            int y  = (cp & 7) ^ (p & 7);
            int m  = 2 * p + (y & 1);
            int k8 = y >> 1;
            gsrc[j]     = gA + (size_t)m * KBYTES + k8 * 16;
            gsrc[2 + j] = gB + (size_t)m * KBYTES + k8 * 16;
            ldst[j]     = lds + (wave * 2 + j) * 1024;           // + slot*16384 (+lane*16 by HW)
            ldst[2 + j] = lds + 65536 + (wave * 2 + j) * 1024;
        }
    }

    // ---- per-lane fragment read bases (swizzled) ----
    const int xsl = (((quad * 2) + (r & 1)) ^ ((r >> 1) & 7)) * 16;
    const char* aBase = lds + wm * 64 + (r >> 1) * 128 + xsl;            // + mi*1024 + slot*16384
    const char* bBase = lds + 65536 + wn * 64 + (r >> 1) * 128 + xsl;    // + ni*1024 + slot*16384

    floatx4 acc[8][4] = {};

    auto STAGE = [&](int tt) {
        const int so = (tt & 3) * 16384;
        const int ko = tt * 64;          // k0 byte offset = tt*32*2
        async_copy16(gsrc[0] + ko, ldst[0] + so);
        async_copy16(gsrc[1] + ko, ldst[1] + so);
        async_copy16(gsrc[2] + ko, ldst[2] + so);
        async_copy16(gsrc[3] + ko, ldst[3] + so);
    };

    auto COMPUTE = [&](int tt) {
        const int so = (tt & 3) * 16384;
        bf16x8 af[8], bfr[4];
#pragma unroll
        for (int mi = 0; mi < 8; ++mi)
            af[mi] = *(const bf16x8*)(aBase + so + mi * 1024);
#pragma unroll
        for (int ni = 0; ni < 4; ++ni)
            bfr[ni] = *(const bf16x8*)(bBase + so + ni * 1024);
        __builtin_amdgcn_s_setprio(1);
#pragma unroll
        for (int mi = 0; mi < 8; ++mi)
#pragma unroll
            for (int ni = 0; ni < 4; ++ni)
                acc[mi][ni] = __builtin_amdgcn_mfma_f32_16x16x32_bf16(
                    af[mi], bfr[ni], acc[mi][ni], 0, 0, 0);
        __builtin_amdgcn_s_setprio(0);
    };

    const int NT = K_DIM / 32;   // 128 K-tiles

    // prologue: fill 3 ring slots; wait until tile 0 landed (2 stages in flight)
    STAGE(0); STAGE(1); STAGE(2);
    asm volatile("s_waitcnt vmcnt(8)" ::: "memory");
    __builtin_amdgcn_s_barrier();

    for (int tt = 0; tt < NT - 3; ++tt) {
        STAGE(tt + 3);                       // overwrites slot (tt-1)&3: reads done last epoch
        COMPUTE(tt);
        asm volatile("s_waitcnt vmcnt(8)" ::: "memory");   // tile tt+1 landed
        __builtin_amdgcn_s_barrier();
    }
    // tail: drain ring
    COMPUTE(NT - 3);
    asm volatile("s_waitcnt vmcnt(4)" ::: "memory");
    __builtin_amdgcn_s_barrier();
    COMPUTE(NT - 2);
    asm volatile("s_waitcnt vmcnt(0)" ::: "memory");
    __builtin_amdgcn_s_barrier();
    COMPUTE(NT - 1);

    // epilogue: C/D layout (m89/m91): n = lane&15, m = quad*4 + reg
#pragma unroll
    for (int mi = 0; mi < 8; ++mi) {
#pragma unroll
        for (int rr = 0; rr < 4; ++rr) {
            int row = tm + wm + mi * 16 + quad * 4 + rr;
            float* cp = C + (size_t)row * N_DIM + tn + wn + r;
#pragma unroll
            for (int ni = 0; ni < 4; ++ni)
                cp[ni * 16] = acc[mi][ni][rr];
        }
    }
}

extern "C" void kernel_launch(void* const* d_in, const int* in_sizes, int n_in,
                              void* d_out, int out_size, void* d_ws, size_t ws_size,
                              hipStream_t stream) {
    const float* x = (const float*)d_in[0];           // (4,2048,4096) fp32
    const float* w = (const float*)d_in[1];           // (11008,4096) fp32
    const float* s = (const float*)d_in[2];           // (86,32) fp32
    float* out = (float*)d_out;                       // (4,2048,11008) fp32

    __bf16* xb = (__bf16*)d_ws;                                        // 67 MB
    __bf16* wb = (__bf16*)((char*)d_ws + (size_t)M_DIM * K_DIM * 2);   // 90 MB

    cvt_x_kernel<<<M_DIM * K_DIM / 8 / 256, 256, 0, stream>>>(x, (bf16x8*)xb);
    cvt_w_kernel<<<N_DIM * K_DIM / 8 / 256, 256, 0, stream>>>(w, s, (bf16x8*)wb);

    dim3 grid((N_DIM / 256) * (M_DIM / 256));   // 43 * 32 = 1376 blocks
    gemm_bt_kernel<<<grid, 512, 0, stream>>>(xb, wb, out);
}